// Round 12
// baseline (282.427 us; speedup 1.0000x reference)
//
#include <hip/hip_runtime.h>
#include <math.h>

#define T_TOK 8192
#define D_DIM 2048
#define E_EXP 64
#define CAP   256
#define NCHUNK 32           // T_TOK / 256
#define TEC   (134217728LL) // T*E*C
#define TE    (T_TOK * E_EXP)
#define KSPLIT 4
#define KLEN   (D_DIM / KSPLIT)
#define EPSV   1.1920929e-7f

__device__ __forceinline__ int swz(int r) { return (r & 7) ^ ((r >> 3) & 7); }

// ---------------- K1: split-K x4 logits GEMM (R10 verbatim) ----------------
__global__ __launch_bounds__(256) void k_gemm(const float* __restrict__ x,
                                              const float* __restrict__ wg,
                                              float* __restrict__ part) {
  __shared__ float xs[32 * 64];
  __shared__ float ws[64 * 64];
  const int tid = threadIdx.x;
  const int row0 = (blockIdx.x >> 2) * 32;
  const int kc = blockIdx.x & 3;
  const int kbase = kc * KLEN;
  const int rr = tid >> 4;
  const int cc = tid & 15;
  const int sA0 = swz(rr), sA1 = swz(rr + 16);
  const int sB0 = swz(cc * 4 + 0), sB1 = swz(cc * 4 + 1);
  const int sB2 = swz(cc * 4 + 2), sB3 = swz(cc * 4 + 3);
  float acc[2][4] = {{0.f, 0.f, 0.f, 0.f}, {0.f, 0.f, 0.f, 0.f}};
  for (int k0 = kbase; k0 < kbase + KLEN; k0 += 64) {
#pragma unroll
    for (int i = 0; i < 2; ++i) {
      const int f = tid + i * 256;
      const int r = f >> 4, g = f & 15;
      const float4 v = *reinterpret_cast<const float4*>(
          &x[(size_t)(row0 + r) * D_DIM + k0 + g * 4]);
      *reinterpret_cast<float4*>(&xs[r * 64 + ((g ^ swz(r)) << 2)]) = v;
    }
#pragma unroll
    for (int i = 0; i < 4; ++i) {
      const int f = tid + i * 256;
      const int r = f >> 4, g = f & 15;
      const float4 v = *reinterpret_cast<const float4*>(
          &wg[(size_t)r * D_DIM + k0 + g * 4]);
      *reinterpret_cast<float4*>(&ws[r * 64 + ((g ^ swz(r)) << 2)]) = v;
    }
    __syncthreads();
#pragma unroll
    for (int g = 0; g < 16; ++g) {
      const float4 a0 = *reinterpret_cast<const float4*>(&xs[rr * 64 + ((g ^ sA0) << 2)]);
      const float4 a1 = *reinterpret_cast<const float4*>(&xs[(rr + 16) * 64 + ((g ^ sA1) << 2)]);
      const float4 b0 = *reinterpret_cast<const float4*>(&ws[(cc * 4 + 0) * 64 + ((g ^ sB0) << 2)]);
      const float4 b1 = *reinterpret_cast<const float4*>(&ws[(cc * 4 + 1) * 64 + ((g ^ sB1) << 2)]);
      const float4 b2 = *reinterpret_cast<const float4*>(&ws[(cc * 4 + 2) * 64 + ((g ^ sB2) << 2)]);
      const float4 b3 = *reinterpret_cast<const float4*>(&ws[(cc * 4 + 3) * 64 + ((g ^ sB3) << 2)]);
      acc[0][0] = fmaf(a0.x, b0.x, acc[0][0]); acc[0][0] = fmaf(a0.y, b0.y, acc[0][0]);
      acc[0][0] = fmaf(a0.z, b0.z, acc[0][0]); acc[0][0] = fmaf(a0.w, b0.w, acc[0][0]);
      acc[0][1] = fmaf(a0.x, b1.x, acc[0][1]); acc[0][1] = fmaf(a0.y, b1.y, acc[0][1]);
      acc[0][1] = fmaf(a0.z, b1.z, acc[0][1]); acc[0][1] = fmaf(a0.w, b1.w, acc[0][1]);
      acc[0][2] = fmaf(a0.x, b2.x, acc[0][2]); acc[0][2] = fmaf(a0.y, b2.y, acc[0][2]);
      acc[0][2] = fmaf(a0.z, b2.z, acc[0][2]); acc[0][2] = fmaf(a0.w, b2.w, acc[0][2]);
      acc[0][3] = fmaf(a0.x, b3.x, acc[0][3]); acc[0][3] = fmaf(a0.y, b3.y, acc[0][3]);
      acc[0][3] = fmaf(a0.z, b3.z, acc[0][3]); acc[0][3] = fmaf(a0.w, b3.w, acc[0][3]);
      acc[1][0] = fmaf(a1.x, b0.x, acc[1][0]); acc[1][0] = fmaf(a1.y, b0.y, acc[1][0]);
      acc[1][0] = fmaf(a1.z, b0.z, acc[1][0]); acc[1][0] = fmaf(a1.w, b0.w, acc[1][0]);
      acc[1][1] = fmaf(a1.x, b1.x, acc[1][1]); acc[1][1] = fmaf(a1.y, b1.y, acc[1][1]);
      acc[1][1] = fmaf(a1.z, b1.z, acc[1][1]); acc[1][1] = fmaf(a1.w, b1.w, acc[1][1]);
      acc[1][2] = fmaf(a1.x, b2.x, acc[1][2]); acc[1][2] = fmaf(a1.y, b2.y, acc[1][2]);
      acc[1][2] = fmaf(a1.z, b2.z, acc[1][2]); acc[1][2] = fmaf(a1.w, b2.w, acc[1][2]);
      acc[1][3] = fmaf(a1.x, b3.x, acc[1][3]); acc[1][3] = fmaf(a1.y, b3.y, acc[1][3]);
      acc[1][3] = fmaf(a1.z, b3.z, acc[1][3]); acc[1][3] = fmaf(a1.w, b3.w, acc[1][3]);
    }
    __syncthreads();
  }
  const float4 o0 = make_float4(acc[0][0], acc[0][1], acc[0][2], acc[0][3]);
  const float4 o1 = make_float4(acc[1][0], acc[1][1], acc[1][2], acc[1][3]);
  float* pbase = part + (size_t)kc * TE;
  *reinterpret_cast<float4*>(&pbase[(size_t)(row0 + rr) * E_EXP + cc * 4]) = o0;
  *reinterpret_cast<float4*>(&pbase[(size_t)(row0 + rr + 16) * E_EXP + cc * 4]) = o1;
}

// ---------------- K2: per-row softmax + top1 + gumbel-top2 (R10 verbatim) ----------------
__global__ __launch_bounds__(256) void k_gate(const float* __restrict__ part,
                                              const float* __restrict__ gumbel,
                                              float* __restrict__ colpart,
                                              int* __restrict__ idx1,
                                              int* __restrict__ idx2,
                                              float* __restrict__ g1v,
                                              float* __restrict__ g2v) {
  const int lane = threadIdx.x & 63;
  const int wave = threadIdx.x >> 6;
  const int gwave = blockIdx.x * 4 + wave;
  float colacc = 0.f;
  for (int i = 0; i < 8; ++i) {
    const int t = gwave + i * 1024;
    const int o = t * 64 + lane;
    const float L = (part[o] + part[TE + o]) + (part[2 * TE + o] + part[3 * TE + o]);
    float m = L;
#pragma unroll
    for (int off = 32; off; off >>= 1) m = fmaxf(m, __shfl_xor(m, off));
    const float e = expf(L - m);
    float s = e;
#pragma unroll
    for (int off = 32; off; off >>= 1) s += __shfl_xor(s, off);
    const float g = e / s;
    colacc += g;
    float v = g; int ix = lane;
#pragma unroll
    for (int off = 32; off; off >>= 1) {
      float v2 = __shfl_xor(v, off); int i2 = __shfl_xor(ix, off);
      if (v2 > v || (v2 == v && i2 < ix)) { v = v2; ix = i2; }
    }
    const int i1 = ix;
    const float gate1 = __shfl(g, i1);
    float nz = L + gumbel[o];
    if (lane == i1) nz = -INFINITY;
    float v2v = nz; int ix2 = lane;
#pragma unroll
    for (int off = 32; off; off >>= 1) {
      float v2 = __shfl_xor(v2v, off); int j2 = __shfl_xor(ix2, off);
      if (v2 > v2v || (v2 == v2v && j2 < ix2)) { v2v = v2; ix2 = j2; }
    }
    const int i2x = ix2;
    const float gate2 = __shfl(g, i2x);
    if (lane == 0) { idx1[t] = i1; idx2[t] = i2x; g1v[t] = gate1; g2v[t] = gate2; }
  }
  __shared__ float cs[4][64];
  cs[wave][lane] = colacc;
  __syncthreads();
  if (wave == 0) {
    float ssum = cs[0][lane] + cs[1][lane] + cs[2][lane] + cs[3][lane];
    colpart[blockIdx.x * 64 + lane] = ssum;
  }
}

// ---------------- K3: local ranks + chunk histograms (R10 verbatim) ----------------
__global__ __launch_bounds__(256) void k_rank(const int* __restrict__ idx1,
                                              const int* __restrict__ idx2,
                                              int* __restrict__ rank1,
                                              int* __restrict__ rank2,
                                              int* __restrict__ hist1,
                                              int* __restrict__ hist2) {
  __shared__ int s1[256], s2[256];
  __shared__ int h1[64], h2[64];
  const int tid = threadIdx.x;
  const int base = blockIdx.x * 256;
  if (tid < 64) { h1[tid] = 0; h2[tid] = 0; }
  s1[tid] = idx1[base + tid];
  s2[tid] = idx2[base + tid];
  __syncthreads();
  const int my1 = s1[tid], my2 = s2[tid];
  int r1 = 0, r2 = 0;
  for (int j = 0; j < 256; ++j) {
    r1 += (j < tid && s1[j] == my1);
    r2 += (j < tid && s2[j] == my2);
  }
  atomicAdd(&h1[my1], 1);
  atomicAdd(&h2[my2], 1);
  rank1[base + tid] = r1;
  rank2[base + tid] = r2;
  __syncthreads();
  if (tid < 64) {
    hist1[blockIdx.x * 64 + tid] = h1[tid];
    hist2[blockIdx.x * 64 + tid] = h2[tid];
  }
}

// ---------------- K4: chunk-prefix offsets + l_aux (writes dout[0] AND ws copy) ----------------
__global__ __launch_bounds__(64) void k_prefix(const int* __restrict__ hist1,
                                               const int* __restrict__ hist2,
                                               const float* __restrict__ colpart,
                                               int* __restrict__ offs1,
                                               int* __restrict__ offs2,
                                               float* __restrict__ lauxw,
                                               float* __restrict__ dout) {
  const int e = threadIdx.x;
  int run = 0;
  for (int c = 0; c < NCHUNK; ++c) { offs1[c * 64 + e] = run; run += hist1[c * 64 + e]; }
  const int total1 = run;
  int run2 = total1;
  for (int c = 0; c < NCHUNK; ++c) { offs2[c * 64 + e] = run2; run2 += hist2[c * 64 + e]; }
  float csum = 0.f;
  for (int b = 0; b < 256; ++b) csum += colpart[b * 64 + e];
  const float me = csum / (float)T_TOK;
  const float ce = (float)total1 / (float)T_TOK;
  float val = me * ce;
#pragma unroll
  for (int o = 32; o; o >>= 1) val += __shfl_xor(val, o);
  if (e == 0) { const float la = val * (float)E_EXP; dout[0] = la; lauxw[0] = la; }
}

// ---------------- K5: materialize — full 1.07 GB output in one coalesced pass ----------------
// 2048 blocks x 256 threads. Wave covers 2 tokens' worth of one output half
// (32768 flats); each inner iteration writes one 1KB (t,e)-row region.
// flat layout: [0]=l_aux, [1..TEC]=combine (idx=flat-1), (TEC..2TEC]=dispatch.
__global__ __launch_bounds__(256) void k_mat(const int* __restrict__ idx1,
                                             const int* __restrict__ idx2,
                                             const float* __restrict__ g1v,
                                             const float* __restrict__ g2v,
                                             const int* __restrict__ rank1,
                                             const int* __restrict__ rank2,
                                             const int* __restrict__ offs1,
                                             const int* __restrict__ offs2,
                                             const float* __restrict__ lauxw,
                                             float* __restrict__ dout) {
  const int lane = threadIdx.x & 63;
  const int w = threadIdx.x >> 6;
  const long long WS = (long long)blockIdx.x * 131072 + (long long)w * 32768;
  const bool firstwave = (blockIdx.x == 0 && w == 0);
  for (int tt = 0; tt < 2; ++tt) {
    const long long base = WS + (long long)tt * 16384;
    const bool half = base >= TEC;                 // false: combine, true: dispatch
    const long long rbase = half ? (base - TEC) : base;
    const int t = (int)(rbase >> 14);
    const int e1 = idx1[t], e2 = idx2[t];
    const int l1 = offs1[(t >> 8) * 64 + e1] + rank1[t];
    const int l2 = offs2[(t >> 8) * 64 + e2] + rank2[t];
    const bool k1 = l1 < CAP, k2 = l2 < CAP;
    const float a = k1 ? g1v[t] : 0.f;
    const float b = k2 ? g2v[t] : 0.f;
    const float dn = fmaxf(a + b, EPSV);
    const float w1v = half ? 1.f : a / dn;
    const float w2v = half ? 1.f : b / dn;
    float* po = dout + base + 4 * lane;
    for (int i = 0; i < 64; ++i) {
      float4 v = make_float4(0.f, 0.f, 0.f, 0.f);
      const bool r1 = k1 && (e1 == i);
      const bool r2 = k2 && (e2 == i);
      if (lane == 0) {
        // element flat = base+i*256 belongs to the PREVIOUS row (c=255), or l_aux
        if (firstwave && tt == 0 && i == 0) {
          v.x = lauxw[0];
        } else if (i == 0) {
          const long long idxp = base - 1;          // idx of flat base (combine idx space)
          const bool hp = idxp >= TEC;
          const long long rp = hp ? (idxp - TEC) : idxp;
          const int tp = (int)(rp >> 14);
          const int ep = (int)((rp >> 8) & 63);
          const int e1p = idx1[tp], e2p = idx2[tp];
          const int l1p = offs1[(tp >> 8) * 64 + e1p] + rank1[tp];
          const int l2p = offs2[(tp >> 8) * 64 + e2p] + rank2[tp];
          const bool k1p = l1p < CAP, k2p = l2p < CAP;
          const float ap = k1p ? g1v[tp] : 0.f;
          const float bp = k2p ? g2v[tp] : 0.f;
          const float dp = fmaxf(ap + bp, EPSV);
          float val = 0.f;
          if (k1p && ep == e1p && l1p == 255) val = hp ? 1.f : ap / dp;
          if (k2p && ep == e2p && l2p == 255) val = hp ? 1.f : bp / dp;
          v.x = val;
        } else {
          const int ep = i - 1;                     // same token, previous row
          if (k1 && ep == e1 && l1 == 255) v.x = w1v;
          if (k2 && ep == e2 && l2 == 255) v.x = w2v;
        }
      } else {
        const int k = 4 * lane - 1;                 // c of j=0 element, this row
        if (r1 && k == l1) v.x = w1v;
        if (r2 && k == l2) v.x = w2v;
      }
      if (r1) {
        const int d = l1 - 4 * lane;                // j=1,2,3 -> c = 4l,4l+1,4l+2
        if (d == 0) v.y = w1v; else if (d == 1) v.z = w1v; else if (d == 2) v.w = w1v;
      }
      if (r2) {
        const int d = l2 - 4 * lane;
        if (d == 0) v.y = w2v; else if (d == 1) v.z = w2v; else if (d == 2) v.w = w2v;
      }
      *reinterpret_cast<float4*>(po) = v;
      po += 256;
    }
    // last flat (= 2*TEC): dispatch (t=8191, e=63, c=255)
    if (blockIdx.x == 2047 && w == 3 && tt == 1 && lane == 63) {
      float val = 0.f;
      if (k1 && e1 == 63 && l1 == 255) val = 1.f;
      if (k2 && e2 == 63 && l2 == 255) val = 1.f;
      dout[2LL * TEC] = val;
    }
  }
}

extern "C" void kernel_launch(void* const* d_in, const int* in_sizes, int n_in,
                              void* d_out, int out_size, void* d_ws, size_t ws_size,
                              hipStream_t stream) {
  const float* x = (const float*)d_in[0];
  const float* wg = (const float*)d_in[1];
  const float* gumbel = (const float*)d_in[2];
  float* dout = (float*)d_out;

  char* p = (char*)d_ws;
  float* part = (float*)p;              p += (size_t)KSPLIT * TE * 4;     // 8 MB
  float* colpart = (float*)p;           p += 256 * 64 * 4;
  float* g1v = (float*)p;               p += T_TOK * 4;
  float* g2v = (float*)p;               p += T_TOK * 4;
  int* idx1 = (int*)p;                  p += T_TOK * 4;
  int* idx2 = (int*)p;                  p += T_TOK * 4;
  int* rank1 = (int*)p;                 p += T_TOK * 4;
  int* rank2 = (int*)p;                 p += T_TOK * 4;
  int* hist1 = (int*)p;                 p += NCHUNK * 64 * 4;
  int* hist2 = (int*)p;                 p += NCHUNK * 64 * 4;
  int* offs1 = (int*)p;                 p += NCHUNK * 64 * 4;
  int* offs2 = (int*)p;                 p += NCHUNK * 64 * 4;
  float* lauxw = (float*)p;             p += 64;

  // no memset: k_mat writes every output element (zeros + sparse values + l_aux)
  k_gemm<<<(T_TOK / 32) * KSPLIT, 256, 0, stream>>>(x, wg, part);
  k_gate<<<256, 256, 0, stream>>>(part, gumbel, colpart, idx1, idx2, g1v, g2v);
  k_rank<<<NCHUNK, 256, 0, stream>>>(idx1, idx2, rank1, rank2, hist1, hist2);
  k_prefix<<<1, 64, 0, stream>>>(hist1, hist2, colpart, offs1, offs2, lauxw, dout);
  k_mat<<<2048, 256, 0, stream>>>(idx1, idx2, g1v, g2v, rank1, rank2,
                                  offs1, offs2, lauxw, dout);
}

// Round 13
// 265.107 us; speedup vs baseline: 1.0653x; 1.0653x over previous
//
#include <hip/hip_runtime.h>
#include <math.h>

#define T_TOK 8192
#define D_DIM 2048
#define E_EXP 64
#define CAP   256
#define NCHUNK 32           // T_TOK / 256
#define TEC   (134217728LL) // T*E*C
#define TE    (T_TOK * E_EXP)
#define KSPLIT 4
#define KLEN   (D_DIM / KSPLIT)
#define EPSV   1.1920929e-7f

__device__ __forceinline__ int swz(int r) { return (r & 7) ^ ((r >> 3) & 7); }

// ---------------- K1: split-K x4 logits GEMM (R10 verbatim) ----------------
__global__ __launch_bounds__(256) void k_gemm(const float* __restrict__ x,
                                              const float* __restrict__ wg,
                                              float* __restrict__ part) {
  __shared__ float xs[32 * 64];
  __shared__ float ws[64 * 64];
  const int tid = threadIdx.x;
  const int row0 = (blockIdx.x >> 2) * 32;
  const int kc = blockIdx.x & 3;
  const int kbase = kc * KLEN;
  const int rr = tid >> 4;
  const int cc = tid & 15;
  const int sA0 = swz(rr), sA1 = swz(rr + 16);
  const int sB0 = swz(cc * 4 + 0), sB1 = swz(cc * 4 + 1);
  const int sB2 = swz(cc * 4 + 2), sB3 = swz(cc * 4 + 3);
  float acc[2][4] = {{0.f, 0.f, 0.f, 0.f}, {0.f, 0.f, 0.f, 0.f}};
  for (int k0 = kbase; k0 < kbase + KLEN; k0 += 64) {
#pragma unroll
    for (int i = 0; i < 2; ++i) {
      const int f = tid + i * 256;
      const int r = f >> 4, g = f & 15;
      const float4 v = *reinterpret_cast<const float4*>(
          &x[(size_t)(row0 + r) * D_DIM + k0 + g * 4]);
      *reinterpret_cast<float4*>(&xs[r * 64 + ((g ^ swz(r)) << 2)]) = v;
    }
#pragma unroll
    for (int i = 0; i < 4; ++i) {
      const int f = tid + i * 256;
      const int r = f >> 4, g = f & 15;
      const float4 v = *reinterpret_cast<const float4*>(
          &wg[(size_t)r * D_DIM + k0 + g * 4]);
      *reinterpret_cast<float4*>(&ws[r * 64 + ((g ^ swz(r)) << 2)]) = v;
    }
    __syncthreads();
#pragma unroll
    for (int g = 0; g < 16; ++g) {
      const float4 a0 = *reinterpret_cast<const float4*>(&xs[rr * 64 + ((g ^ sA0) << 2)]);
      const float4 a1 = *reinterpret_cast<const float4*>(&xs[(rr + 16) * 64 + ((g ^ sA1) << 2)]);
      const float4 b0 = *reinterpret_cast<const float4*>(&ws[(cc * 4 + 0) * 64 + ((g ^ sB0) << 2)]);
      const float4 b1 = *reinterpret_cast<const float4*>(&ws[(cc * 4 + 1) * 64 + ((g ^ sB1) << 2)]);
      const float4 b2 = *reinterpret_cast<const float4*>(&ws[(cc * 4 + 2) * 64 + ((g ^ sB2) << 2)]);
      const float4 b3 = *reinterpret_cast<const float4*>(&ws[(cc * 4 + 3) * 64 + ((g ^ sB3) << 2)]);
      acc[0][0] = fmaf(a0.x, b0.x, acc[0][0]); acc[0][0] = fmaf(a0.y, b0.y, acc[0][0]);
      acc[0][0] = fmaf(a0.z, b0.z, acc[0][0]); acc[0][0] = fmaf(a0.w, b0.w, acc[0][0]);
      acc[0][1] = fmaf(a0.x, b1.x, acc[0][1]); acc[0][1] = fmaf(a0.y, b1.y, acc[0][1]);
      acc[0][1] = fmaf(a0.z, b1.z, acc[0][1]); acc[0][1] = fmaf(a0.w, b1.w, acc[0][1]);
      acc[0][2] = fmaf(a0.x, b2.x, acc[0][2]); acc[0][2] = fmaf(a0.y, b2.y, acc[0][2]);
      acc[0][2] = fmaf(a0.z, b2.z, acc[0][2]); acc[0][2] = fmaf(a0.w, b2.w, acc[0][2]);
      acc[0][3] = fmaf(a0.x, b3.x, acc[0][3]); acc[0][3] = fmaf(a0.y, b3.y, acc[0][3]);
      acc[0][3] = fmaf(a0.z, b3.z, acc[0][3]); acc[0][3] = fmaf(a0.w, b3.w, acc[0][3]);
      acc[1][0] = fmaf(a1.x, b0.x, acc[1][0]); acc[1][0] = fmaf(a1.y, b0.y, acc[1][0]);
      acc[1][0] = fmaf(a1.z, b0.z, acc[1][0]); acc[1][0] = fmaf(a1.w, b0.w, acc[1][0]);
      acc[1][1] = fmaf(a1.x, b1.x, acc[1][1]); acc[1][1] = fmaf(a1.y, b1.y, acc[1][1]);
      acc[1][1] = fmaf(a1.z, b1.z, acc[1][1]); acc[1][1] = fmaf(a1.w, b1.w, acc[1][1]);
      acc[1][2] = fmaf(a1.x, b2.x, acc[1][2]); acc[1][2] = fmaf(a1.y, b2.y, acc[1][2]);
      acc[1][2] = fmaf(a1.z, b2.z, acc[1][2]); acc[1][2] = fmaf(a1.w, b2.w, acc[1][2]);
      acc[1][3] = fmaf(a1.x, b3.x, acc[1][3]); acc[1][3] = fmaf(a1.y, b3.y, acc[1][3]);
      acc[1][3] = fmaf(a1.z, b3.z, acc[1][3]); acc[1][3] = fmaf(a1.w, b3.w, acc[1][3]);
    }
    __syncthreads();
  }
  const float4 o0 = make_float4(acc[0][0], acc[0][1], acc[0][2], acc[0][3]);
  const float4 o1 = make_float4(acc[1][0], acc[1][1], acc[1][2], acc[1][3]);
  float* pbase = part + (size_t)kc * TE;
  *reinterpret_cast<float4*>(&pbase[(size_t)(row0 + rr) * E_EXP + cc * 4]) = o0;
  *reinterpret_cast<float4*>(&pbase[(size_t)(row0 + rr + 16) * E_EXP + cc * 4]) = o1;
}

// ---------------- K2: per-row softmax + top1 + gumbel-top2 (R10 + sync-zeroing) ----------------
__global__ __launch_bounds__(256) void k_gate(const float* __restrict__ part,
                                              const float* __restrict__ gumbel,
                                              float* __restrict__ colpart,
                                              int* __restrict__ idx1,
                                              int* __restrict__ idx2,
                                              float* __restrict__ g1v,
                                              float* __restrict__ g2v,
                                              unsigned int* __restrict__ sync) {
  // reset the tail kernel's sync words (tail runs strictly after gate)
  if (blockIdx.x == 0 && threadIdx.x < 2) atomicExch(&sync[threadIdx.x], 0u);
  const int lane = threadIdx.x & 63;
  const int wave = threadIdx.x >> 6;
  const int gwave = blockIdx.x * 4 + wave;
  float colacc = 0.f;
  for (int i = 0; i < 8; ++i) {
    const int t = gwave + i * 1024;
    const int o = t * 64 + lane;
    const float L = (part[o] + part[TE + o]) + (part[2 * TE + o] + part[3 * TE + o]);
    float m = L;
#pragma unroll
    for (int off = 32; off; off >>= 1) m = fmaxf(m, __shfl_xor(m, off));
    const float e = expf(L - m);
    float s = e;
#pragma unroll
    for (int off = 32; off; off >>= 1) s += __shfl_xor(s, off);
    const float g = e / s;
    colacc += g;
    float v = g; int ix = lane;
#pragma unroll
    for (int off = 32; off; off >>= 1) {
      float v2 = __shfl_xor(v, off); int i2 = __shfl_xor(ix, off);
      if (v2 > v || (v2 == v && i2 < ix)) { v = v2; ix = i2; }
    }
    const int i1 = ix;
    const float gate1 = __shfl(g, i1);
    float nz = L + gumbel[o];
    if (lane == i1) nz = -INFINITY;
    float v2v = nz; int ix2 = lane;
#pragma unroll
    for (int off = 32; off; off >>= 1) {
      float v2 = __shfl_xor(v2v, off); int j2 = __shfl_xor(ix2, off);
      if (v2 > v2v || (v2 == v2v && j2 < ix2)) { v2v = v2; ix2 = j2; }
    }
    const int i2x = ix2;
    const float gate2 = __shfl(g, i2x);
    if (lane == 0) { idx1[t] = i1; idx2[t] = i2x; g1v[t] = gate1; g2v[t] = gate2; }
  }
  __shared__ float cs[4][64];
  cs[wave][lane] = colacc;
  __syncthreads();
  if (wave == 0) {
    float ssum = cs[0][lane] + cs[1][lane] + cs[2][lane] + cs[3][lane];
    colpart[blockIdx.x * 64 + lane] = ssum;
  }
}

// ---------------- K3: fused rank + prefix + l_aux + scatter (one kernel) ----------------
// 32 blocks x 256 threads; block = one 256-token chunk. Software barrier:
// all 32 blocks are trivially co-resident on 256 CUs; cross-block data goes
// through device-scope atomics only (XCD-L2 safe).
__global__ __launch_bounds__(256) void k_tail(const int* __restrict__ idx1,
                                              const int* __restrict__ idx2,
                                              const float* __restrict__ g1v,
                                              const float* __restrict__ g2v,
                                              const float* __restrict__ colpart,
                                              int* __restrict__ histG1,
                                              int* __restrict__ histG2,
                                              int* __restrict__ offsG1,
                                              int* __restrict__ offsG2,
                                              unsigned int* __restrict__ sync,
                                              float* __restrict__ dout) {
  __shared__ int s1[256], s2[256];
  __shared__ int h1[64], h2[64];
  __shared__ int ticket_s;
  const int tid = threadIdx.x;
  const int bid = blockIdx.x;
  const int base = bid * 256;
  if (tid < 64) { h1[tid] = 0; h2[tid] = 0; }
  s1[tid] = idx1[base + tid];
  s2[tid] = idx2[base + tid];
  __syncthreads();
  // ---- phase A: local ranks (registers) + chunk histogram ----
  const int my1 = s1[tid], my2 = s2[tid];
  int r1 = 0, r2 = 0;
  for (int j = 0; j < 256; ++j) {
    r1 += (j < tid && s1[j] == my1);
    r2 += (j < tid && s2[j] == my2);
  }
  atomicAdd(&h1[my1], 1);
  atomicAdd(&h2[my2], 1);
  __syncthreads();
  if (tid < 64) {
    atomicExch(&histG1[bid * 64 + tid], h1[tid]);   // device-coherent publish
    atomicExch(&histG2[bid * 64 + tid], h2[tid]);
  }
  __threadfence();
  __syncthreads();
  if (tid == 0) ticket_s = (int)atomicAdd(&sync[0], 1u);
  __syncthreads();
  // ---- phase B: last-arriving block does prefix + l_aux ----
  if (ticket_s == NCHUNK - 1) {
    if (tid < 64) {
      const int e = tid;
      int hh1[NCHUNK], hh2[NCHUNK];
#pragma unroll
      for (int c = 0; c < NCHUNK; ++c) hh1[c] = atomicAdd(&histG1[c * 64 + e], 0);
#pragma unroll
      for (int c = 0; c < NCHUNK; ++c) hh2[c] = atomicAdd(&histG2[c * 64 + e], 0);
      int run = 0;
#pragma unroll
      for (int c = 0; c < NCHUNK; ++c) { atomicExch(&offsG1[c * 64 + e], run); run += hh1[c]; }
      const int total1 = run;
      int run2 = total1;  // locations2 offset includes sum(mask1, axis=0)
#pragma unroll
      for (int c = 0; c < NCHUNK; ++c) { atomicExch(&offsG2[c * 64 + e], run2); run2 += hh2[c]; }
      float csum = 0.f;
      for (int b = 0; b < 256; ++b) csum += colpart[b * 64 + e];
      const float me = csum / (float)T_TOK;
      const float ce = (float)total1 / (float)T_TOK;
      float val = me * ce;
#pragma unroll
      for (int o = 32; o; o >>= 1) val += __shfl_xor(val, o);
      if (e == 0) dout[0] = val * (float)E_EXP;
    }
    __threadfence();
    __syncthreads();
    if (tid == 0) atomicExch(&sync[1], 1u);
  }
  // ---- barrier: wait for offs ----
  if (tid == 0) { while (atomicAdd(&sync[1], 0u) == 0u) { } }
  __syncthreads();
  // ---- phase C: scatter this chunk's tokens ----
  const int t = base + tid;
  const int loc1 = atomicAdd(&offsG1[bid * 64 + my1], 0) + r1;
  const int loc2 = atomicAdd(&offsG2[bid * 64 + my2], 0) + r2;
  const bool k1 = loc1 < CAP;
  const bool k2 = loc2 < CAP;
  const float a = k1 ? g1v[t] : 0.f;
  const float b = k2 ? g2v[t] : 0.f;
  const float denom = fmaxf(a + b, EPSV);
  if (k1) {
    const long long o = 1LL + ((long long)t * 64 + my1) * 256 + loc1;
    dout[o] = a / denom;
    dout[o + TEC] = 1.0f;
  }
  if (k2) {
    const long long o = 1LL + ((long long)t * 64 + my2) * 256 + loc2;
    dout[o] = b / denom;
    dout[o + TEC] = 1.0f;
  }
}

extern "C" void kernel_launch(void* const* d_in, const int* in_sizes, int n_in,
                              void* d_out, int out_size, void* d_ws, size_t ws_size,
                              hipStream_t stream) {
  const float* x = (const float*)d_in[0];
  const float* wg = (const float*)d_in[1];
  const float* gumbel = (const float*)d_in[2];
  float* dout = (float*)d_out;

  char* p = (char*)d_ws;
  float* part = (float*)p;              p += (size_t)KSPLIT * TE * 4;     // 8 MB
  float* colpart = (float*)p;           p += 256 * 64 * 4;                // 64 KB
  float* g1v = (float*)p;               p += T_TOK * 4;
  float* g2v = (float*)p;               p += T_TOK * 4;
  int* idx1 = (int*)p;                  p += T_TOK * 4;
  int* idx2 = (int*)p;                  p += T_TOK * 4;
  int* histG1 = (int*)p;                p += NCHUNK * 64 * 4;
  int* histG2 = (int*)p;                p += NCHUNK * 64 * 4;
  int* offsG1 = (int*)p;                p += NCHUNK * 64 * 4;
  int* offsG2 = (int*)p;                p += NCHUNK * 64 * 4;
  unsigned int* sync = (unsigned int*)p; p += 256;

  // zero-fill the (sparse) 1.07 GB output — the structural floor of this op
  hipMemsetAsync(d_out, 0, (size_t)out_size * sizeof(float), stream);

  k_gemm<<<(T_TOK / 32) * KSPLIT, 256, 0, stream>>>(x, wg, part);
  k_gate<<<256, 256, 0, stream>>>(part, gumbel, colpart, idx1, idx2, g1v, g2v, sync);
  k_tail<<<NCHUNK, 256, 0, stream>>>(idx1, idx2, g1v, g2v, colpart,
                                     histG1, histG2, offsG1, offsG2, sync, dout);
}

// Round 14
// 262.994 us; speedup vs baseline: 1.0739x; 1.0080x over previous
//
#include <hip/hip_runtime.h>
#include <math.h>

#define T_TOK 8192
#define D_DIM 2048
#define E_EXP 64
#define CAP   256
#define NCHUNK 32           // T_TOK / 256
#define TEC   (134217728LL) // T*E*C
#define TE    (T_TOK * E_EXP)
#define KSPLIT 4
#define KLEN   (D_DIM / KSPLIT)

__device__ __forceinline__ int swz(int r) { return (r & 7) ^ ((r >> 3) & 7); }

// ---------------- K1: split-K x4 logits GEMM ----------------
// 1024 blocks: rowblk = bid>>2 (32 rows), kc = bid&3 (K in [kc*512, kc*512+512)).
__global__ __launch_bounds__(256) void k_gemm(const float* __restrict__ x,
                                              const float* __restrict__ wg,
                                              float* __restrict__ part) {
  __shared__ float xs[32 * 64];
  __shared__ float ws[64 * 64];
  const int tid = threadIdx.x;
  const int row0 = (blockIdx.x >> 2) * 32;
  const int kc = blockIdx.x & 3;
  const int kbase = kc * KLEN;
  const int rr = tid >> 4;   // 0..15 -> rows rr, rr+16
  const int cc = tid & 15;   // cols cc*4..cc*4+3
  const int sA0 = swz(rr), sA1 = swz(rr + 16);
  const int sB0 = swz(cc * 4 + 0), sB1 = swz(cc * 4 + 1);
  const int sB2 = swz(cc * 4 + 2), sB3 = swz(cc * 4 + 3);
  float acc[2][4] = {{0.f, 0.f, 0.f, 0.f}, {0.f, 0.f, 0.f, 0.f}};
  for (int k0 = kbase; k0 < kbase + KLEN; k0 += 64) {
#pragma unroll
    for (int i = 0; i < 2; ++i) {
      const int f = tid + i * 256;
      const int r = f >> 4, g = f & 15;
      const float4 v = *reinterpret_cast<const float4*>(
          &x[(size_t)(row0 + r) * D_DIM + k0 + g * 4]);
      *reinterpret_cast<float4*>(&xs[r * 64 + ((g ^ swz(r)) << 2)]) = v;
    }
#pragma unroll
    for (int i = 0; i < 4; ++i) {
      const int f = tid + i * 256;
      const int r = f >> 4, g = f & 15;
      const float4 v = *reinterpret_cast<const float4*>(
          &wg[(size_t)r * D_DIM + k0 + g * 4]);
      *reinterpret_cast<float4*>(&ws[r * 64 + ((g ^ swz(r)) << 2)]) = v;
    }
    __syncthreads();
#pragma unroll
    for (int g = 0; g < 16; ++g) {
      const float4 a0 = *reinterpret_cast<const float4*>(&xs[rr * 64 + ((g ^ sA0) << 2)]);
      const float4 a1 = *reinterpret_cast<const float4*>(&xs[(rr + 16) * 64 + ((g ^ sA1) << 2)]);
      const float4 b0 = *reinterpret_cast<const float4*>(&ws[(cc * 4 + 0) * 64 + ((g ^ sB0) << 2)]);
      const float4 b1 = *reinterpret_cast<const float4*>(&ws[(cc * 4 + 1) * 64 + ((g ^ sB1) << 2)]);
      const float4 b2 = *reinterpret_cast<const float4*>(&ws[(cc * 4 + 2) * 64 + ((g ^ sB2) << 2)]);
      const float4 b3 = *reinterpret_cast<const float4*>(&ws[(cc * 4 + 3) * 64 + ((g ^ sB3) << 2)]);
      acc[0][0] = fmaf(a0.x, b0.x, acc[0][0]); acc[0][0] = fmaf(a0.y, b0.y, acc[0][0]);
      acc[0][0] = fmaf(a0.z, b0.z, acc[0][0]); acc[0][0] = fmaf(a0.w, b0.w, acc[0][0]);
      acc[0][1] = fmaf(a0.x, b1.x, acc[0][1]); acc[0][1] = fmaf(a0.y, b1.y, acc[0][1]);
      acc[0][1] = fmaf(a0.z, b1.z, acc[0][1]); acc[0][1] = fmaf(a0.w, b1.w, acc[0][1]);
      acc[0][2] = fmaf(a0.x, b2.x, acc[0][2]); acc[0][2] = fmaf(a0.y, b2.y, acc[0][2]);
      acc[0][2] = fmaf(a0.z, b2.z, acc[0][2]); acc[0][2] = fmaf(a0.w, b2.w, acc[0][2]);
      acc[0][3] = fmaf(a0.x, b3.x, acc[0][3]); acc[0][3] = fmaf(a0.y, b3.y, acc[0][3]);
      acc[0][3] = fmaf(a0.z, b3.z, acc[0][3]); acc[0][3] = fmaf(a0.w, b3.w, acc[0][3]);
      acc[1][0] = fmaf(a1.x, b0.x, acc[1][0]); acc[1][0] = fmaf(a1.y, b0.y, acc[1][0]);
      acc[1][0] = fmaf(a1.z, b0.z, acc[1][0]); acc[1][0] = fmaf(a1.w, b0.w, acc[1][0]);
      acc[1][1] = fmaf(a1.x, b1.x, acc[1][1]); acc[1][1] = fmaf(a1.y, b1.y, acc[1][1]);
      acc[1][1] = fmaf(a1.z, b1.z, acc[1][1]); acc[1][1] = fmaf(a1.w, b1.w, acc[1][1]);
      acc[1][2] = fmaf(a1.x, b2.x, acc[1][2]); acc[1][2] = fmaf(a1.y, b2.y, acc[1][2]);
      acc[1][2] = fmaf(a1.z, b2.z, acc[1][2]); acc[1][2] = fmaf(a1.w, b2.w, acc[1][2]);
      acc[1][3] = fmaf(a1.x, b3.x, acc[1][3]); acc[1][3] = fmaf(a1.y, b3.y, acc[1][3]);
      acc[1][3] = fmaf(a1.z, b3.z, acc[1][3]); acc[1][3] = fmaf(a1.w, b3.w, acc[1][3]);
    }
    __syncthreads();
  }
  const float4 o0 = make_float4(acc[0][0], acc[0][1], acc[0][2], acc[0][3]);
  const float4 o1 = make_float4(acc[1][0], acc[1][1], acc[1][2], acc[1][3]);
  float* pbase = part + (size_t)kc * TE;
  *reinterpret_cast<float4*>(&pbase[(size_t)(row0 + rr) * E_EXP + cc * 4]) = o0;
  *reinterpret_cast<float4*>(&pbase[(size_t)(row0 + rr + 16) * E_EXP + cc * 4]) = o1;
}

// ---------------- K2: per-row softmax + top1 + gumbel-top2 ----------------
// grid 256 x 256 threads (4 waves). Sums the 4 split-K partials in fixed order.
__global__ __launch_bounds__(256) void k_gate(const float* __restrict__ part,
                                              const float* __restrict__ gumbel,
                                              float* __restrict__ colpart,
                                              int* __restrict__ idx1,
                                              int* __restrict__ idx2,
                                              float* __restrict__ g1v,
                                              float* __restrict__ g2v) {
  const int lane = threadIdx.x & 63;
  const int wave = threadIdx.x >> 6;
  const int gwave = blockIdx.x * 4 + wave;  // 0..1023
  float colacc = 0.f;
  for (int i = 0; i < 8; ++i) {
    const int t = gwave + i * 1024;
    const int o = t * 64 + lane;
    const float L = (part[o] + part[TE + o]) + (part[2 * TE + o] + part[3 * TE + o]);
    float m = L;
#pragma unroll
    for (int off = 32; off; off >>= 1) m = fmaxf(m, __shfl_xor(m, off));
    const float e = expf(L - m);
    float s = e;
#pragma unroll
    for (int off = 32; off; off >>= 1) s += __shfl_xor(s, off);
    const float g = e / s;
    colacc += g;
    float v = g; int ix = lane;
#pragma unroll
    for (int off = 32; off; off >>= 1) {
      float v2 = __shfl_xor(v, off); int i2 = __shfl_xor(ix, off);
      if (v2 > v || (v2 == v && i2 < ix)) { v = v2; ix = i2; }
    }
    const int i1 = ix;
    const float gate1 = __shfl(g, i1);
    float nz = L + gumbel[o];
    if (lane == i1) nz = -INFINITY;
    float v2v = nz; int ix2 = lane;
#pragma unroll
    for (int off = 32; off; off >>= 1) {
      float v2 = __shfl_xor(v2v, off); int j2 = __shfl_xor(ix2, off);
      if (v2 > v2v || (v2 == v2v && j2 < ix2)) { v2v = v2; ix2 = j2; }
    }
    const int i2x = ix2;
    const float gate2 = __shfl(g, i2x);
    if (lane == 0) { idx1[t] = i1; idx2[t] = i2x; g1v[t] = gate1; g2v[t] = gate2; }
  }
  __shared__ float cs[4][64];
  cs[wave][lane] = colacc;
  __syncthreads();
  if (wave == 0) {
    float ssum = cs[0][lane] + cs[1][lane] + cs[2][lane] + cs[3][lane];
    colpart[blockIdx.x * 64 + lane] = ssum;
  }
}

// ---------------- K3: local ranks + chunk histograms ----------------
__global__ __launch_bounds__(256) void k_rank(const int* __restrict__ idx1,
                                              const int* __restrict__ idx2,
                                              int* __restrict__ rank1,
                                              int* __restrict__ rank2,
                                              int* __restrict__ hist1,
                                              int* __restrict__ hist2) {
  __shared__ int s1[256], s2[256];
  __shared__ int h1[64], h2[64];
  const int tid = threadIdx.x;
  const int base = blockIdx.x * 256;
  if (tid < 64) { h1[tid] = 0; h2[tid] = 0; }
  s1[tid] = idx1[base + tid];
  s2[tid] = idx2[base + tid];
  __syncthreads();
  const int my1 = s1[tid], my2 = s2[tid];
  int r1 = 0, r2 = 0;
  for (int j = 0; j < 256; ++j) {
    r1 += (j < tid && s1[j] == my1);
    r2 += (j < tid && s2[j] == my2);
  }
  atomicAdd(&h1[my1], 1);
  atomicAdd(&h2[my2], 1);
  rank1[base + tid] = r1;
  rank2[base + tid] = r2;
  __syncthreads();
  if (tid < 64) {
    hist1[blockIdx.x * 64 + tid] = h1[tid];
    hist2[blockIdx.x * 64 + tid] = h2[tid];
  }
}

// ---------------- K4: chunk-prefix offsets + l_aux ----------------
__global__ __launch_bounds__(64) void k_prefix(const int* __restrict__ hist1,
                                               const int* __restrict__ hist2,
                                               const float* __restrict__ colpart,
                                               int* __restrict__ offs1,
                                               int* __restrict__ offs2,
                                               float* __restrict__ dout) {
  const int e = threadIdx.x;
  int run = 0;
  for (int c = 0; c < NCHUNK; ++c) { offs1[c * 64 + e] = run; run += hist1[c * 64 + e]; }
  const int total1 = run;
  int run2 = total1;  // locations2 offset includes sum(mask1, axis=0)
  for (int c = 0; c < NCHUNK; ++c) { offs2[c * 64 + e] = run2; run2 += hist2[c * 64 + e]; }
  float csum = 0.f;
  for (int b = 0; b < 256; ++b) csum += colpart[b * 64 + e];
  const float me = csum / (float)T_TOK;
  const float ce = (float)total1 / (float)T_TOK;
  float val = me * ce;
#pragma unroll
  for (int o = 32; o; o >>= 1) val += __shfl_xor(val, o);
  if (e == 0) dout[0] = val * (float)E_EXP;  // mean(me*ce)*E*E = sum*E
}

// ---------------- K5: sparse scatter of combine weights + dispatch ----------------
__global__ __launch_bounds__(256) void k_scatter(const int* __restrict__ idx1,
                                                 const int* __restrict__ idx2,
                                                 const float* __restrict__ g1v,
                                                 const float* __restrict__ g2v,
                                                 const int* __restrict__ rank1,
                                                 const int* __restrict__ rank2,
                                                 const int* __restrict__ offs1,
                                                 const int* __restrict__ offs2,
                                                 float* __restrict__ dout) {
  const int t = blockIdx.x * 256 + threadIdx.x;
  const int c = t >> 8;
  const int e1 = idx1[t], e2 = idx2[t];
  const int loc1 = offs1[c * 64 + e1] + rank1[t];
  const int loc2 = offs2[c * 64 + e2] + rank2[t];
  const bool k1 = loc1 < CAP;
  const bool k2 = loc2 < CAP;
  const float a = k1 ? g1v[t] : 0.f;
  const float b = k2 ? g2v[t] : 0.f;
  const float denom = fmaxf(a + b, 1.1920929e-7f);  // FLT_EPSILON
  if (k1) {
    const long long o = 1LL + ((long long)t * 64 + e1) * 256 + loc1;
    dout[o] = a / denom;
    dout[o + TEC] = 1.0f;
  }
  if (k2) {
    const long long o = 1LL + ((long long)t * 64 + e2) * 256 + loc2;
    dout[o] = b / denom;
    dout[o + TEC] = 1.0f;
  }
}

extern "C" void kernel_launch(void* const* d_in, const int* in_sizes, int n_in,
                              void* d_out, int out_size, void* d_ws, size_t ws_size,
                              hipStream_t stream) {
  const float* x = (const float*)d_in[0];
  const float* wg = (const float*)d_in[1];
  const float* gumbel = (const float*)d_in[2];
  float* dout = (float*)d_out;

  // workspace layout (aligned chunks)
  char* p = (char*)d_ws;
  float* part = (float*)p;              p += (size_t)KSPLIT * TE * 4;     // 8 MB
  float* colpart = (float*)p;           p += 256 * 64 * 4;                // 64 KB
  float* g1v = (float*)p;               p += T_TOK * 4;
  float* g2v = (float*)p;               p += T_TOK * 4;
  int* idx1 = (int*)p;                  p += T_TOK * 4;
  int* idx2 = (int*)p;                  p += T_TOK * 4;
  int* rank1 = (int*)p;                 p += T_TOK * 4;
  int* rank2 = (int*)p;                 p += T_TOK * 4;
  int* hist1 = (int*)p;                 p += NCHUNK * 64 * 4;
  int* hist2 = (int*)p;                 p += NCHUNK * 64 * 4;
  int* offs1 = (int*)p;                 p += NCHUNK * 64 * 4;
  int* offs2 = (int*)p;                 p += NCHUNK * 64 * 4;

  // zero-fill the (sparse) 1.07 GB output — the structural floor of this op
  hipMemsetAsync(d_out, 0, (size_t)out_size * sizeof(float), stream);

  k_gemm<<<(T_TOK / 32) * KSPLIT, 256, 0, stream>>>(x, wg, part);
  k_gate<<<256, 256, 0, stream>>>(part, gumbel, colpart, idx1, idx2, g1v, g2v);
  k_rank<<<NCHUNK, 256, 0, stream>>>(idx1, idx2, rank1, rank2, hist1, hist2);
  k_prefix<<<1, 64, 0, stream>>>(hist1, hist2, colpart, offs1, offs2, dout);
  k_scatter<<<NCHUNK, 256, 0, stream>>>(idx1, idx2, g1v, g2v, rank1, rank2,
                                        offs1, offs2, dout);
}

// Round 15
// 253.645 us; speedup vs baseline: 1.1135x; 1.0369x over previous
//
#include <hip/hip_runtime.h>
#include <math.h>

#define T_TOK 8192
#define D_DIM 2048
#define E_EXP 64
#define CAP   256
#define NCHUNK 32           // T_TOK / 256
#define TEC   (134217728LL) // T*E*C
#define TE    (T_TOK * E_EXP)
#define KSPLIT 4
#define KLEN   (D_DIM / KSPLIT)

__device__ __forceinline__ int swz(int r) { return (r & 7) ^ ((r >> 3) & 7); }

// ---------------- K1: split-K x4 logits GEMM, BM=64, 4x4 acc/thread ----------------
// 512 blocks: rowblk = bid>>2 (64 rows), kc = bid&3 (K in [kc*512, kc*512+512)).
// Staging layout/pattern identical to R10; inner loop reads 8 b128 per 64 FMAs.
__global__ __launch_bounds__(256) void k_gemm(const float* __restrict__ x,
                                              const float* __restrict__ wg,
                                              float* __restrict__ part) {
  __shared__ float xs[64 * 64];
  __shared__ float ws[64 * 64];
  const int tid = threadIdx.x;
  const int row0 = (blockIdx.x >> 2) * 64;
  const int kc = blockIdx.x & 3;
  const int kbase = kc * KLEN;
  const int tr = tid & 15;   // output rows tr+16j
  const int tc = tid >> 4;   // output cols tc*4..tc*4+3
  const int sA[4] = {swz(tr), swz(tr + 16), swz(tr + 32), swz(tr + 48)};
  const int sB[4] = {swz(tc * 4 + 0), swz(tc * 4 + 1), swz(tc * 4 + 2), swz(tc * 4 + 3)};
  float acc[4][4] = {{0.f, 0.f, 0.f, 0.f}, {0.f, 0.f, 0.f, 0.f},
                     {0.f, 0.f, 0.f, 0.f}, {0.f, 0.f, 0.f, 0.f}};
  for (int k0 = kbase; k0 < kbase + KLEN; k0 += 64) {
#pragma unroll
    for (int i = 0; i < 4; ++i) {
      const int f = tid + i * 256;
      const int r = f >> 4, g = f & 15;
      const float4 v = *reinterpret_cast<const float4*>(
          &x[(size_t)(row0 + r) * D_DIM + k0 + g * 4]);
      *reinterpret_cast<float4*>(&xs[r * 64 + ((g ^ swz(r)) << 2)]) = v;
    }
#pragma unroll
    for (int i = 0; i < 4; ++i) {
      const int f = tid + i * 256;
      const int r = f >> 4, g = f & 15;
      const float4 v = *reinterpret_cast<const float4*>(
          &wg[(size_t)r * D_DIM + k0 + g * 4]);
      *reinterpret_cast<float4*>(&ws[r * 64 + ((g ^ swz(r)) << 2)]) = v;
    }
    __syncthreads();
#pragma unroll
    for (int g = 0; g < 16; ++g) {
      float4 a[4], b[4];
#pragma unroll
      for (int j = 0; j < 4; ++j) {
        a[j] = *reinterpret_cast<const float4*>(&xs[(tr + 16 * j) * 64 + ((g ^ sA[j]) << 2)]);
        b[j] = *reinterpret_cast<const float4*>(&ws[(tc * 4 + j) * 64 + ((g ^ sB[j]) << 2)]);
      }
#pragma unroll
      for (int jr = 0; jr < 4; ++jr)
#pragma unroll
        for (int jc = 0; jc < 4; ++jc) {
          acc[jr][jc] = fmaf(a[jr].x, b[jc].x, acc[jr][jc]);
          acc[jr][jc] = fmaf(a[jr].y, b[jc].y, acc[jr][jc]);
          acc[jr][jc] = fmaf(a[jr].z, b[jc].z, acc[jr][jc]);
          acc[jr][jc] = fmaf(a[jr].w, b[jc].w, acc[jr][jc]);
        }
    }
    __syncthreads();
  }
  float* pbase = part + (size_t)kc * TE;
#pragma unroll
  for (int jr = 0; jr < 4; ++jr) {
    const float4 o = make_float4(acc[jr][0], acc[jr][1], acc[jr][2], acc[jr][3]);
    *reinterpret_cast<float4*>(&pbase[(size_t)(row0 + tr + 16 * jr) * E_EXP + tc * 4]) = o;
  }
}

// ---------------- K2: per-row softmax + top1 + gumbel-top2 (R14 verbatim) ----------------
__global__ __launch_bounds__(256) void k_gate(const float* __restrict__ part,
                                              const float* __restrict__ gumbel,
                                              float* __restrict__ colpart,
                                              int* __restrict__ idx1,
                                              int* __restrict__ idx2,
                                              float* __restrict__ g1v,
                                              float* __restrict__ g2v) {
  const int lane = threadIdx.x & 63;
  const int wave = threadIdx.x >> 6;
  const int gwave = blockIdx.x * 4 + wave;  // 0..1023
  float colacc = 0.f;
  for (int i = 0; i < 8; ++i) {
    const int t = gwave + i * 1024;
    const int o = t * 64 + lane;
    const float L = (part[o] + part[TE + o]) + (part[2 * TE + o] + part[3 * TE + o]);
    float m = L;
#pragma unroll
    for (int off = 32; off; off >>= 1) m = fmaxf(m, __shfl_xor(m, off));
    const float e = expf(L - m);
    float s = e;
#pragma unroll
    for (int off = 32; off; off >>= 1) s += __shfl_xor(s, off);
    const float g = e / s;
    colacc += g;
    float v = g; int ix = lane;
#pragma unroll
    for (int off = 32; off; off >>= 1) {
      float v2 = __shfl_xor(v, off); int i2 = __shfl_xor(ix, off);
      if (v2 > v || (v2 == v && i2 < ix)) { v = v2; ix = i2; }
    }
    const int i1 = ix;
    const float gate1 = __shfl(g, i1);
    float nz = L + gumbel[o];
    if (lane == i1) nz = -INFINITY;
    float v2v = nz; int ix2 = lane;
#pragma unroll
    for (int off = 32; off; off >>= 1) {
      float v2 = __shfl_xor(v2v, off); int j2 = __shfl_xor(ix2, off);
      if (v2 > v2v || (v2 == v2v && j2 < ix2)) { v2v = v2; ix2 = j2; }
    }
    const int i2x = ix2;
    const float gate2 = __shfl(g, i2x);
    if (lane == 0) { idx1[t] = i1; idx2[t] = i2x; g1v[t] = gate1; g2v[t] = gate2; }
  }
  __shared__ float cs[4][64];
  cs[wave][lane] = colacc;
  __syncthreads();
  if (wave == 0) {
    float ssum = cs[0][lane] + cs[1][lane] + cs[2][lane] + cs[3][lane];
    colpart[blockIdx.x * 64 + lane] = ssum;
  }
}

// ---------------- K3: local ranks + chunk histograms (R14 verbatim) ----------------
__global__ __launch_bounds__(256) void k_rank(const int* __restrict__ idx1,
                                              const int* __restrict__ idx2,
                                              int* __restrict__ rank1,
                                              int* __restrict__ rank2,
                                              int* __restrict__ hist1,
                                              int* __restrict__ hist2) {
  __shared__ int s1[256], s2[256];
  __shared__ int h1[64], h2[64];
  const int tid = threadIdx.x;
  const int base = blockIdx.x * 256;
  if (tid < 64) { h1[tid] = 0; h2[tid] = 0; }
  s1[tid] = idx1[base + tid];
  s2[tid] = idx2[base + tid];
  __syncthreads();
  const int my1 = s1[tid], my2 = s2[tid];
  int r1 = 0, r2 = 0;
  for (int j = 0; j < 256; ++j) {
    r1 += (j < tid && s1[j] == my1);
    r2 += (j < tid && s2[j] == my2);
  }
  atomicAdd(&h1[my1], 1);
  atomicAdd(&h2[my2], 1);
  rank1[base + tid] = r1;
  rank2[base + tid] = r2;
  __syncthreads();
  if (tid < 64) {
    hist1[blockIdx.x * 64 + tid] = h1[tid];
    hist2[blockIdx.x * 64 + tid] = h2[tid];
  }
}

// ---------------- K4: chunk-prefix offsets + l_aux (R14 verbatim) ----------------
__global__ __launch_bounds__(64) void k_prefix(const int* __restrict__ hist1,
                                               const int* __restrict__ hist2,
                                               const float* __restrict__ colpart,
                                               int* __restrict__ offs1,
                                               int* __restrict__ offs2,
                                               float* __restrict__ dout) {
  const int e = threadIdx.x;
  int run = 0;
  for (int c = 0; c < NCHUNK; ++c) { offs1[c * 64 + e] = run; run += hist1[c * 64 + e]; }
  const int total1 = run;
  int run2 = total1;  // locations2 offset includes sum(mask1, axis=0)
  for (int c = 0; c < NCHUNK; ++c) { offs2[c * 64 + e] = run2; run2 += hist2[c * 64 + e]; }
  float csum = 0.f;
  for (int b = 0; b < 256; ++b) csum += colpart[b * 64 + e];
  const float me = csum / (float)T_TOK;
  const float ce = (float)total1 / (float)T_TOK;
  float val = me * ce;
#pragma unroll
  for (int o = 32; o; o >>= 1) val += __shfl_xor(val, o);
  if (e == 0) dout[0] = val * (float)E_EXP;  // mean(me*ce)*E*E = sum*E
}

// ---------------- K5: sparse scatter of combine weights + dispatch (R14 verbatim) ----------------
__global__ __launch_bounds__(256) void k_scatter(const int* __restrict__ idx1,
                                                 const int* __restrict__ idx2,
                                                 const float* __restrict__ g1v,
                                                 const float* __restrict__ g2v,
                                                 const int* __restrict__ rank1,
                                                 const int* __restrict__ rank2,
                                                 const int* __restrict__ offs1,
                                                 const int* __restrict__ offs2,
                                                 float* __restrict__ dout) {
  const int t = blockIdx.x * 256 + threadIdx.x;
  const int c = t >> 8;
  const int e1 = idx1[t], e2 = idx2[t];
  const int loc1 = offs1[c * 64 + e1] + rank1[t];
  const int loc2 = offs2[c * 64 + e2] + rank2[t];
  const bool k1 = loc1 < CAP;
  const bool k2 = loc2 < CAP;
  const float a = k1 ? g1v[t] : 0.f;
  const float b = k2 ? g2v[t] : 0.f;
  const float denom = fmaxf(a + b, 1.1920929e-7f);  // FLT_EPSILON
  if (k1) {
    const long long o = 1LL + ((long long)t * 64 + e1) * 256 + loc1;
    dout[o] = a / denom;
    dout[o + TEC] = 1.0f;
  }
  if (k2) {
    const long long o = 1LL + ((long long)t * 64 + e2) * 256 + loc2;
    dout[o] = b / denom;
    dout[o + TEC] = 1.0f;
  }
}

extern "C" void kernel_launch(void* const* d_in, const int* in_sizes, int n_in,
                              void* d_out, int out_size, void* d_ws, size_t ws_size,
                              hipStream_t stream) {
  const float* x = (const float*)d_in[0];
  const float* wg = (const float*)d_in[1];
  const float* gumbel = (const float*)d_in[2];
  float* dout = (float*)d_out;

  // workspace layout (aligned chunks)
  char* p = (char*)d_ws;
  float* part = (float*)p;              p += (size_t)KSPLIT * TE * 4;     // 8 MB
  float* colpart = (float*)p;           p += 256 * 64 * 4;                // 64 KB
  float* g1v = (float*)p;               p += T_TOK * 4;
  float* g2v = (float*)p;               p += T_TOK * 4;
  int* idx1 = (int*)p;                  p += T_TOK * 4;
  int* idx2 = (int*)p;                  p += T_TOK * 4;
  int* rank1 = (int*)p;                 p += T_TOK * 4;
  int* rank2 = (int*)p;                 p += T_TOK * 4;
  int* hist1 = (int*)p;                 p += NCHUNK * 64 * 4;
  int* hist2 = (int*)p;                 p += NCHUNK * 64 * 4;
  int* offs1 = (int*)p;                 p += NCHUNK * 64 * 4;
  int* offs2 = (int*)p;                 p += NCHUNK * 64 * 4;

  // zero-fill the (sparse) 1.07 GB output — the structural floor of this op
  hipMemsetAsync(d_out, 0, (size_t)out_size * sizeof(float), stream);

  k_gemm<<<(T_TOK / 64) * KSPLIT, 256, 0, stream>>>(x, wg, part);
  k_gate<<<256, 256, 0, stream>>>(part, gumbel, colpart, idx1, idx2, g1v, g2v);
  k_rank<<<NCHUNK, 256, 0, stream>>>(idx1, idx2, rank1, rank2, hist1, hist2);
  k_prefix<<<1, 64, 0, stream>>>(hist1, hist2, colpart, offs1, offs2, dout);
  k_scatter<<<NCHUNK, 256, 0, stream>>>(idx1, idx2, g1v, g2v, rank1, rank2,
                                        offs1, offs2, dout);
}

// Round 16
// 251.738 us; speedup vs baseline: 1.1219x; 1.0076x over previous
//
#include <hip/hip_runtime.h>
#include <math.h>

#define T_TOK 8192
#define D_DIM 2048
#define E_EXP 64
#define CAP   256
#define NCHUNK 32           // T_TOK / 256
#define TEC   (134217728LL) // T*E*C
#define TE    (T_TOK * E_EXP)
#define KSPLIT 4
#define KLEN   (D_DIM / KSPLIT)

__device__ __forceinline__ int swz(int r) { return (r & 7) ^ ((r >> 3) & 7); }

// ---------------- K1: split-K x4 logits GEMM, BM=64, 4x4 acc/thread (R15 verbatim) ----------------
__global__ __launch_bounds__(256) void k_gemm(const float* __restrict__ x,
                                              const float* __restrict__ wg,
                                              float* __restrict__ part) {
  __shared__ float xs[64 * 64];
  __shared__ float ws[64 * 64];
  const int tid = threadIdx.x;
  const int row0 = (blockIdx.x >> 2) * 64;
  const int kc = blockIdx.x & 3;
  const int kbase = kc * KLEN;
  const int tr = tid & 15;   // output rows tr+16j
  const int tc = tid >> 4;   // output cols tc*4..tc*4+3
  const int sA[4] = {swz(tr), swz(tr + 16), swz(tr + 32), swz(tr + 48)};
  const int sB[4] = {swz(tc * 4 + 0), swz(tc * 4 + 1), swz(tc * 4 + 2), swz(tc * 4 + 3)};
  float acc[4][4] = {{0.f, 0.f, 0.f, 0.f}, {0.f, 0.f, 0.f, 0.f},
                     {0.f, 0.f, 0.f, 0.f}, {0.f, 0.f, 0.f, 0.f}};
  for (int k0 = kbase; k0 < kbase + KLEN; k0 += 64) {
#pragma unroll
    for (int i = 0; i < 4; ++i) {
      const int f = tid + i * 256;
      const int r = f >> 4, g = f & 15;
      const float4 v = *reinterpret_cast<const float4*>(
          &x[(size_t)(row0 + r) * D_DIM + k0 + g * 4]);
      *reinterpret_cast<float4*>(&xs[r * 64 + ((g ^ swz(r)) << 2)]) = v;
    }
#pragma unroll
    for (int i = 0; i < 4; ++i) {
      const int f = tid + i * 256;
      const int r = f >> 4, g = f & 15;
      const float4 v = *reinterpret_cast<const float4*>(
          &wg[(size_t)r * D_DIM + k0 + g * 4]);
      *reinterpret_cast<float4*>(&ws[r * 64 + ((g ^ swz(r)) << 2)]) = v;
    }
    __syncthreads();
#pragma unroll
    for (int g = 0; g < 16; ++g) {
      float4 a[4], b[4];
#pragma unroll
      for (int j = 0; j < 4; ++j) {
        a[j] = *reinterpret_cast<const float4*>(&xs[(tr + 16 * j) * 64 + ((g ^ sA[j]) << 2)]);
        b[j] = *reinterpret_cast<const float4*>(&ws[(tc * 4 + j) * 64 + ((g ^ sB[j]) << 2)]);
      }
#pragma unroll
      for (int jr = 0; jr < 4; ++jr)
#pragma unroll
        for (int jc = 0; jc < 4; ++jc) {
          acc[jr][jc] = fmaf(a[jr].x, b[jc].x, acc[jr][jc]);
          acc[jr][jc] = fmaf(a[jr].y, b[jc].y, acc[jr][jc]);
          acc[jr][jc] = fmaf(a[jr].z, b[jc].z, acc[jr][jc]);
          acc[jr][jc] = fmaf(a[jr].w, b[jc].w, acc[jr][jc]);
        }
    }
    __syncthreads();
  }
  float* pbase = part + (size_t)kc * TE;
#pragma unroll
  for (int jr = 0; jr < 4; ++jr) {
    const float4 o = make_float4(acc[jr][0], acc[jr][1], acc[jr][2], acc[jr][3]);
    *reinterpret_cast<float4*>(&pbase[(size_t)(row0 + tr + 16 * jr) * E_EXP + tc * 4]) = o;
  }
}

// ---------------- K2: per-row softmax + top1 + gumbel-top2 (R15 verbatim) ----------------
__global__ __launch_bounds__(256) void k_gate(const float* __restrict__ part,
                                              const float* __restrict__ gumbel,
                                              float* __restrict__ colpart,
                                              int* __restrict__ idx1,
                                              int* __restrict__ idx2,
                                              float* __restrict__ g1v,
                                              float* __restrict__ g2v) {
  const int lane = threadIdx.x & 63;
  const int wave = threadIdx.x >> 6;
  const int gwave = blockIdx.x * 4 + wave;  // 0..1023
  float colacc = 0.f;
  for (int i = 0; i < 8; ++i) {
    const int t = gwave + i * 1024;
    const int o = t * 64 + lane;
    const float L = (part[o] + part[TE + o]) + (part[2 * TE + o] + part[3 * TE + o]);
    float m = L;
#pragma unroll
    for (int off = 32; off; off >>= 1) m = fmaxf(m, __shfl_xor(m, off));
    const float e = expf(L - m);
    float s = e;
#pragma unroll
    for (int off = 32; off; off >>= 1) s += __shfl_xor(s, off);
    const float g = e / s;
    colacc += g;
    float v = g; int ix = lane;
#pragma unroll
    for (int off = 32; off; off >>= 1) {
      float v2 = __shfl_xor(v, off); int i2 = __shfl_xor(ix, off);
      if (v2 > v || (v2 == v && i2 < ix)) { v = v2; ix = i2; }
    }
    const int i1 = ix;
    const float gate1 = __shfl(g, i1);
    float nz = L + gumbel[o];
    if (lane == i1) nz = -INFINITY;
    float v2v = nz; int ix2 = lane;
#pragma unroll
    for (int off = 32; off; off >>= 1) {
      float v2 = __shfl_xor(v2v, off); int j2 = __shfl_xor(ix2, off);
      if (v2 > v2v || (v2 == v2v && j2 < ix2)) { v2v = v2; ix2 = j2; }
    }
    const int i2x = ix2;
    const float gate2 = __shfl(g, i2x);
    if (lane == 0) { idx1[t] = i1; idx2[t] = i2x; g1v[t] = gate1; g2v[t] = gate2; }
  }
  __shared__ float cs[4][64];
  cs[wave][lane] = colacc;
  __syncthreads();
  if (wave == 0) {
    float ssum = cs[0][lane] + cs[1][lane] + cs[2][lane] + cs[3][lane];
    colpart[blockIdx.x * 64 + lane] = ssum;
  }
}

// ---------------- K3: local ranks + chunk histograms (R15 verbatim) ----------------
__global__ __launch_bounds__(256) void k_rank(const int* __restrict__ idx1,
                                              const int* __restrict__ idx2,
                                              int* __restrict__ rank1,
                                              int* __restrict__ rank2,
                                              int* __restrict__ hist1,
                                              int* __restrict__ hist2) {
  __shared__ int s1[256], s2[256];
  __shared__ int h1[64], h2[64];
  const int tid = threadIdx.x;
  const int base = blockIdx.x * 256;
  if (tid < 64) { h1[tid] = 0; h2[tid] = 0; }
  s1[tid] = idx1[base + tid];
  s2[tid] = idx2[base + tid];
  __syncthreads();
  const int my1 = s1[tid], my2 = s2[tid];
  int r1 = 0, r2 = 0;
  for (int j = 0; j < 256; ++j) {
    r1 += (j < tid && s1[j] == my1);
    r2 += (j < tid && s2[j] == my2);
  }
  atomicAdd(&h1[my1], 1);
  atomicAdd(&h2[my2], 1);
  rank1[base + tid] = r1;
  rank2[base + tid] = r2;
  __syncthreads();
  if (tid < 64) {
    hist1[blockIdx.x * 64 + tid] = h1[tid];
    hist2[blockIdx.x * 64 + tid] = h2[tid];
  }
}

// ---------------- K4: scatter + per-block prefix + l_aux (prefix kernel folded in) ----------------
// 32 blocks x 256 threads; block = one 256-token chunk. Threads 0-63 (wave 0)
// recompute this chunk's expert offsets from the chunk histograms in the same
// fixed serial order k_prefix used (deterministic, bit-identical). Block 0
// additionally computes l_aux. Then all threads scatter.
__global__ __launch_bounds__(256) void k_scatter(const int* __restrict__ idx1,
                                                 const int* __restrict__ idx2,
                                                 const float* __restrict__ g1v,
                                                 const float* __restrict__ g2v,
                                                 const int* __restrict__ rank1,
                                                 const int* __restrict__ rank2,
                                                 const int* __restrict__ hist1,
                                                 const int* __restrict__ hist2,
                                                 const float* __restrict__ colpart,
                                                 float* __restrict__ dout) {
  __shared__ int offs1_s[64], offs2_s[64];
  const int tid = threadIdx.x;
  const int bid = blockIdx.x;
  if (tid < 64) {
    const int e = tid;
    int run1 = 0, pre1 = 0;
    for (int c = 0; c < NCHUNK; ++c) {
      if (c == bid) pre1 = run1;
      run1 += hist1[c * 64 + e];
    }
    const int total1 = run1;   // sum(mask1, axis=0)[e]
    int pre2 = 0;
    for (int c = 0; c < bid; ++c) pre2 += hist2[c * 64 + e];
    offs1_s[e] = pre1;
    offs2_s[e] = total1 + pre2;
    if (bid == 0) {
      float csum = 0.f;
      for (int b = 0; b < 256; ++b) csum += colpart[b * 64 + e];
      const float me = csum / (float)T_TOK;
      const float ce = (float)total1 / (float)T_TOK;
      float val = me * ce;
#pragma unroll
      for (int o = 32; o; o >>= 1) val += __shfl_xor(val, o);
      if (e == 0) dout[0] = val * (float)E_EXP;  // mean(me*ce)*E*E = sum*E
    }
  }
  __syncthreads();
  const int t = bid * 256 + tid;
  const int e1 = idx1[t], e2 = idx2[t];
  const int loc1 = offs1_s[e1] + rank1[t];
  const int loc2 = offs2_s[e2] + rank2[t];
  const bool k1 = loc1 < CAP;
  const bool k2 = loc2 < CAP;
  const float a = k1 ? g1v[t] : 0.f;
  const float b = k2 ? g2v[t] : 0.f;
  const float denom = fmaxf(a + b, 1.1920929e-7f);  // FLT_EPSILON
  if (k1) {
    const long long o = 1LL + ((long long)t * 64 + e1) * 256 + loc1;
    dout[o] = a / denom;
    dout[o + TEC] = 1.0f;
  }
  if (k2) {
    const long long o = 1LL + ((long long)t * 64 + e2) * 256 + loc2;
    dout[o] = b / denom;
    dout[o + TEC] = 1.0f;
  }
}

extern "C" void kernel_launch(void* const* d_in, const int* in_sizes, int n_in,
                              void* d_out, int out_size, void* d_ws, size_t ws_size,
                              hipStream_t stream) {
  const float* x = (const float*)d_in[0];
  const float* wg = (const float*)d_in[1];
  const float* gumbel = (const float*)d_in[2];
  float* dout = (float*)d_out;

  // workspace layout (aligned chunks)
  char* p = (char*)d_ws;
  float* part = (float*)p;              p += (size_t)KSPLIT * TE * 4;     // 8 MB
  float* colpart = (float*)p;           p += 256 * 64 * 4;                // 64 KB
  float* g1v = (float*)p;               p += T_TOK * 4;
  float* g2v = (float*)p;               p += T_TOK * 4;
  int* idx1 = (int*)p;                  p += T_TOK * 4;
  int* idx2 = (int*)p;                  p += T_TOK * 4;
  int* rank1 = (int*)p;                 p += T_TOK * 4;
  int* rank2 = (int*)p;                 p += T_TOK * 4;
  int* hist1 = (int*)p;                 p += NCHUNK * 64 * 4;
  int* hist2 = (int*)p;                 p += NCHUNK * 64 * 4;

  // zero-fill the (sparse) 1.07 GB output — the structural floor of this op
  hipMemsetAsync(d_out, 0, (size_t)out_size * sizeof(float), stream);

  k_gemm<<<(T_TOK / 64) * KSPLIT, 256, 0, stream>>>(x, wg, part);
  k_gate<<<256, 256, 0, stream>>>(part, gumbel, colpart, idx1, idx2, g1v, g2v);
  k_rank<<<NCHUNK, 256, 0, stream>>>(idx1, idx2, rank1, rank2, hist1, hist2);
  k_scatter<<<NCHUNK, 256, 0, stream>>>(idx1, idx2, g1v, g2v, rank1, rank2,
                                        hist1, hist2, colpart, dout);
}

// Round 17
// 244.683 us; speedup vs baseline: 1.1543x; 1.0288x over previous
//
#include <hip/hip_runtime.h>
#include <math.h>

#define T_TOK 8192
#define D_DIM 2048
#define E_EXP 64
#define CAP   256
#define NCHUNK 32           // T_TOK / 256
#define TEC   (134217728LL) // T*E*C
#define TE    (T_TOK * E_EXP)
#define KSPLIT 4
#define KLEN   (D_DIM / KSPLIT)

__device__ __forceinline__ int swz(int r) { return (r & 7) ^ ((r >> 3) & 7); }

// ---------------- K1: split-K x4 logits GEMM, BM=64, 4x4 acc/thread (R15 verbatim) ----------------
__global__ __launch_bounds__(256) void k_gemm(const float* __restrict__ x,
                                              const float* __restrict__ wg,
                                              float* __restrict__ part) {
  __shared__ float xs[64 * 64];
  __shared__ float ws[64 * 64];
  const int tid = threadIdx.x;
  const int row0 = (blockIdx.x >> 2) * 64;
  const int kc = blockIdx.x & 3;
  const int kbase = kc * KLEN;
  const int tr = tid & 15;   // output rows tr+16j
  const int tc = tid >> 4;   // output cols tc*4..tc*4+3
  const int sA[4] = {swz(tr), swz(tr + 16), swz(tr + 32), swz(tr + 48)};
  const int sB[4] = {swz(tc * 4 + 0), swz(tc * 4 + 1), swz(tc * 4 + 2), swz(tc * 4 + 3)};
  float acc[4][4] = {{0.f, 0.f, 0.f, 0.f}, {0.f, 0.f, 0.f, 0.f},
                     {0.f, 0.f, 0.f, 0.f}, {0.f, 0.f, 0.f, 0.f}};
  for (int k0 = kbase; k0 < kbase + KLEN; k0 += 64) {
#pragma unroll
    for (int i = 0; i < 4; ++i) {
      const int f = tid + i * 256;
      const int r = f >> 4, g = f & 15;
      const float4 v = *reinterpret_cast<const float4*>(
          &x[(size_t)(row0 + r) * D_DIM + k0 + g * 4]);
      *reinterpret_cast<float4*>(&xs[r * 64 + ((g ^ swz(r)) << 2)]) = v;
    }
#pragma unroll
    for (int i = 0; i < 4; ++i) {
      const int f = tid + i * 256;
      const int r = f >> 4, g = f & 15;
      const float4 v = *reinterpret_cast<const float4*>(
          &wg[(size_t)r * D_DIM + k0 + g * 4]);
      *reinterpret_cast<float4*>(&ws[r * 64 + ((g ^ swz(r)) << 2)]) = v;
    }
    __syncthreads();
#pragma unroll
    for (int g = 0; g < 16; ++g) {
      float4 a[4], b[4];
#pragma unroll
      for (int j = 0; j < 4; ++j) {
        a[j] = *reinterpret_cast<const float4*>(&xs[(tr + 16 * j) * 64 + ((g ^ sA[j]) << 2)]);
        b[j] = *reinterpret_cast<const float4*>(&ws[(tc * 4 + j) * 64 + ((g ^ sB[j]) << 2)]);
      }
#pragma unroll
      for (int jr = 0; jr < 4; ++jr)
#pragma unroll
        for (int jc = 0; jc < 4; ++jc) {
          acc[jr][jc] = fmaf(a[jr].x, b[jc].x, acc[jr][jc]);
          acc[jr][jc] = fmaf(a[jr].y, b[jc].y, acc[jr][jc]);
          acc[jr][jc] = fmaf(a[jr].z, b[jc].z, acc[jr][jc]);
          acc[jr][jc] = fmaf(a[jr].w, b[jc].w, acc[jr][jc]);
        }
    }
    __syncthreads();
  }
  float* pbase = part + (size_t)kc * TE;
#pragma unroll
  for (int jr = 0; jr < 4; ++jr) {
    const float4 o = make_float4(acc[jr][0], acc[jr][1], acc[jr][2], acc[jr][3]);
    *reinterpret_cast<float4*>(&pbase[(size_t)(row0 + tr + 16 * jr) * E_EXP + tc * 4]) = o;
  }
}

// ---------------- K2: per-row softmax + top1 + gumbel-top2 ----------------
// v2: fused max+argmax (argmax(softmax)=argmax(L)); gate1 = 1/s (bit-identical,
// since e[i1]=exp(m-m)=1); 2-token ILP per iteration (A/B chains interleave).
__global__ __launch_bounds__(256) void k_gate(const float* __restrict__ part,
                                              const float* __restrict__ gumbel,
                                              float* __restrict__ colpart,
                                              int* __restrict__ idx1,
                                              int* __restrict__ idx2,
                                              float* __restrict__ g1v,
                                              float* __restrict__ g2v) {
  const int lane = threadIdx.x & 63;
  const int wave = threadIdx.x >> 6;
  const int gwave = blockIdx.x * 4 + wave;  // 0..1023
  float colacc = 0.f;
  for (int i = 0; i < 4; ++i) {
    const int tA = gwave + i * 1024;
    const int tB = tA + 4096;
    const int oA = tA * 64 + lane;
    const int oB = tB * 64 + lane;
    const float LA = (part[oA] + part[TE + oA]) + (part[2 * TE + oA] + part[3 * TE + oA]);
    const float LB = (part[oB] + part[TE + oB]) + (part[2 * TE + oB] + part[3 * TE + oB]);
    const float gnA = gumbel[oA];
    const float gnB = gumbel[oB];
    // fused max + first-argmax over L (ties -> lowest index)
    float mA = LA; int iA = lane;
    float mB = LB; int iB = lane;
#pragma unroll
    for (int off = 32; off; off >>= 1) {
      const float vA = __shfl_xor(mA, off); const int jA = __shfl_xor(iA, off);
      const float vB = __shfl_xor(mB, off); const int jB = __shfl_xor(iB, off);
      if (vA > mA || (vA == mA && jA < iA)) { mA = vA; iA = jA; }
      if (vB > mB || (vB == mB && jB < iB)) { mB = vB; iB = jB; }
    }
    const float eA = expf(LA - mA);
    const float eB = expf(LB - mB);
    float sA = eA, sB = eB;
#pragma unroll
    for (int off = 32; off; off >>= 1) {
      sA += __shfl_xor(sA, off);
      sB += __shfl_xor(sB, off);
    }
    colacc += eA / sA + eB / sB;
    const float gate1A = 1.0f / sA;   // g[i1] = exp(m-m)/s = 1/s exactly
    const float gate1B = 1.0f / sB;
    // argmax2 over noised logits, expert i1 masked out
    float nA = LA + gnA; if (lane == iA) nA = -INFINITY;
    float nB = LB + gnB; if (lane == iB) nB = -INFINITY;
    float vA2 = nA; int iA2 = lane;
    float vB2 = nB; int iB2 = lane;
#pragma unroll
    for (int off = 32; off; off >>= 1) {
      const float wA = __shfl_xor(vA2, off); const int kA = __shfl_xor(iA2, off);
      const float wB = __shfl_xor(vB2, off); const int kB = __shfl_xor(iB2, off);
      if (wA > vA2 || (wA == vA2 && kA < iA2)) { vA2 = wA; iA2 = kA; }
      if (wB > vB2 || (wB == vB2 && kB < iB2)) { vB2 = wB; iB2 = kB; }
    }
    const float gate2A = __shfl(eA, iA2) / sA;   // = g[i2] (s wave-uniform)
    const float gate2B = __shfl(eB, iB2) / sB;
    if (lane == 0) {
      idx1[tA] = iA; idx2[tA] = iA2; g1v[tA] = gate1A; g2v[tA] = gate2A;
      idx1[tB] = iB; idx2[tB] = iB2; g1v[tB] = gate1B; g2v[tB] = gate2B;
    }
  }
  __shared__ float cs[4][64];
  cs[wave][lane] = colacc;
  __syncthreads();
  if (wave == 0) {
    float ssum = cs[0][lane] + cs[1][lane] + cs[2][lane] + cs[3][lane];
    colpart[blockIdx.x * 64 + lane] = ssum;
  }
}

// ---------------- K3: local ranks + chunk histograms (R16 verbatim) ----------------
__global__ __launch_bounds__(256) void k_rank(const int* __restrict__ idx1,
                                              const int* __restrict__ idx2,
                                              int* __restrict__ rank1,
                                              int* __restrict__ rank2,
                                              int* __restrict__ hist1,
                                              int* __restrict__ hist2) {
  __shared__ int s1[256], s2[256];
  __shared__ int h1[64], h2[64];
  const int tid = threadIdx.x;
  const int base = blockIdx.x * 256;
  if (tid < 64) { h1[tid] = 0; h2[tid] = 0; }
  s1[tid] = idx1[base + tid];
  s2[tid] = idx2[base + tid];
  __syncthreads();
  const int my1 = s1[tid], my2 = s2[tid];
  int r1 = 0, r2 = 0;
  for (int j = 0; j < 256; ++j) {
    r1 += (j < tid && s1[j] == my1);
    r2 += (j < tid && s2[j] == my2);
  }
  atomicAdd(&h1[my1], 1);
  atomicAdd(&h2[my2], 1);
  rank1[base + tid] = r1;
  rank2[base + tid] = r2;
  __syncthreads();
  if (tid < 64) {
    hist1[blockIdx.x * 64 + tid] = h1[tid];
    hist2[blockIdx.x * 64 + tid] = h2[tid];
  }
}

// ---------------- K4: scatter + per-block prefix + l_aux (R16 verbatim) ----------------
__global__ __launch_bounds__(256) void k_scatter(const int* __restrict__ idx1,
                                                 const int* __restrict__ idx2,
                                                 const float* __restrict__ g1v,
                                                 const float* __restrict__ g2v,
                                                 const int* __restrict__ rank1,
                                                 const int* __restrict__ rank2,
                                                 const int* __restrict__ hist1,
                                                 const int* __restrict__ hist2,
                                                 const float* __restrict__ colpart,
                                                 float* __restrict__ dout) {
  __shared__ int offs1_s[64], offs2_s[64];
  const int tid = threadIdx.x;
  const int bid = blockIdx.x;
  if (tid < 64) {
    const int e = tid;
    int run1 = 0, pre1 = 0;
    for (int c = 0; c < NCHUNK; ++c) {
      if (c == bid) pre1 = run1;
      run1 += hist1[c * 64 + e];
    }
    const int total1 = run1;   // sum(mask1, axis=0)[e]
    int pre2 = 0;
    for (int c = 0; c < bid; ++c) pre2 += hist2[c * 64 + e];
    offs1_s[e] = pre1;
    offs2_s[e] = total1 + pre2;
    if (bid == 0) {
      float csum = 0.f;
      for (int b = 0; b < 256; ++b) csum += colpart[b * 64 + e];
      const float me = csum / (float)T_TOK;
      const float ce = (float)total1 / (float)T_TOK;
      float val = me * ce;
#pragma unroll
      for (int o = 32; o; o >>= 1) val += __shfl_xor(val, o);
      if (e == 0) dout[0] = val * (float)E_EXP;  // mean(me*ce)*E*E = sum*E
    }
  }
  __syncthreads();
  const int t = bid * 256 + tid;
  const int e1 = idx1[t], e2 = idx2[t];
  const int loc1 = offs1_s[e1] + rank1[t];
  const int loc2 = offs2_s[e2] + rank2[t];
  const bool k1 = loc1 < CAP;
  const bool k2 = loc2 < CAP;
  const float a = k1 ? g1v[t] : 0.f;
  const float b = k2 ? g2v[t] : 0.f;
  const float denom = fmaxf(a + b, 1.1920929e-7f);  // FLT_EPSILON
  if (k1) {
    const long long o = 1LL + ((long long)t * 64 + e1) * 256 + loc1;
    dout[o] = a / denom;
    dout[o + TEC] = 1.0f;
  }
  if (k2) {
    const long long o = 1LL + ((long long)t * 64 + e2) * 256 + loc2;
    dout[o] = b / denom;
    dout[o + TEC] = 1.0f;
  }
}

extern "C" void kernel_launch(void* const* d_in, const int* in_sizes, int n_in,
                              void* d_out, int out_size, void* d_ws, size_t ws_size,
                              hipStream_t stream) {
  const float* x = (const float*)d_in[0];
  const float* wg = (const float*)d_in[1];
  const float* gumbel = (const float*)d_in[2];
  float* dout = (float*)d_out;

  // workspace layout (aligned chunks)
  char* p = (char*)d_ws;
  float* part = (float*)p;              p += (size_t)KSPLIT * TE * 4;     // 8 MB
  float* colpart = (float*)p;           p += 256 * 64 * 4;                // 64 KB
  float* g1v = (float*)p;               p += T_TOK * 4;
  float* g2v = (float*)p;               p += T_TOK * 4;
  int* idx1 = (int*)p;                  p += T_TOK * 4;
  int* idx2 = (int*)p;                  p += T_TOK * 4;
  int* rank1 = (int*)p;                 p += T_TOK * 4;
  int* rank2 = (int*)p;                 p += T_TOK * 4;
  int* hist1 = (int*)p;                 p += NCHUNK * 64 * 4;
  int* hist2 = (int*)p;                 p += NCHUNK * 64 * 4;

  // zero-fill the (sparse) 1.07 GB output — the structural floor of this op
  hipMemsetAsync(d_out, 0, (size_t)out_size * sizeof(float), stream);

  k_gemm<<<(T_TOK / 64) * KSPLIT, 256, 0, stream>>>(x, wg, part);
  k_gate<<<256, 256, 0, stream>>>(part, gumbel, colpart, idx1, idx2, g1v, g2v);
  k_rank<<<NCHUNK, 256, 0, stream>>>(idx1, idx2, rank1, rank2, hist1, hist2);
  k_scatter<<<NCHUNK, 256, 0, stream>>>(idx1, idx2, g1v, g2v, rank1, rank2,
                                        hist1, hist2, colpart, dout);
}